// Round 9
// baseline (4141.533 us; speedup 1.0000x reference)
//
#include <hip/hip_runtime.h>
#include <hip/hip_cooperative_groups.h>

// LSTM: B=64, T=256, IN=512, H=1024 (4H=4096), OUT=512. I/O f32.
// Round-19 = r18 + out-proj (A2) and out-store (B2) moved into the
// barrier-wait shadow, made RACE-FREE by a TRIPLE h buffer:
//   h_t -> buf[t%3]; h_{t-1} = buf[(t+2)%3]. The buffer holding
//   h_{t-1} is next overwritten at step t+2's phase B, which is
//   ordered after barrier(t+1), which needs OUR flag(t+1), which we
//   set after our shadow-A2 -> shadow reads of h_{t-1} can never race
//   the overwrite, with no dispatch-order assumptions.
// Serial chain per step is now: h-gate-loop -> sync -> B (cell update
// + publish) -> flag store -> [shadow: A2 -> sync -> B2 -> x-pre] ->
// poll -> fence -> sync. A2 (~1.5-2us) leaves the critical path.
// r18 evidence: x-pre shadow alone was +0.4us only -> wait was short;
// this round moves the biggest remaining movable phase into it.
// MFMA accumulation order unchanged (x ks=0..15 then h ks=0..31) ->
// bitwise-identical numerics (absmax 7.8e-3).
// ws: [0,16K) flags; [64K, +768K) h triple buffer (hi/lo planes).

#define B_   64
#define T_   256
#define IN_  512
#define H_   1024
#define G4_  4096
#define OUT_ 512
#define KTOT 1536   // IN_ + H_

typedef __bf16 bf8v  __attribute__((ext_vector_type(8)));
typedef float  f4v   __attribute__((ext_vector_type(4)));

__device__ __forceinline__ float sigm(float x) { return 1.f / (1.f + __expf(-x)); }
__device__ __forceinline__ float tanh_f(float x) { return 1.f - 2.f / (__expf(2.f * x) + 1.f); }

// Write-through store of one bf16, bypassing L1 (sc0) and L2 (sc1):
// value is visible at the LLC (agent coherence point) when vmcnt retires.
__device__ __forceinline__ void store_bf16_wt(__bf16* p, __bf16 v) {
    union { __bf16 b; unsigned short s; } cv; cv.b = v;
    unsigned w = cv.s;
    asm volatile("global_store_short %0, %1, off sc0 sc1"
                 :: "v"(p), "v"(w) : "memory");
}

// x-part of the gate GEMM for timestep tt (r12 order).
#define X_PRE(tt, xa0, xa1)                                                   \
    {                                                                         \
        const float* xrow = xs + ((size_t)rowA * T_ + (size_t)(tt)) * IN_ + kq; \
        _Pragma("unroll")                                                     \
        for (int ks = 0; ks < 16; ++ks) {                                     \
            f4v v0 = *(const f4v*)(xrow + ks * 32);                           \
            f4v v1 = *(const f4v*)(xrow + ks * 32 + 4);                       \
            bf8v ah, al;                                                      \
            _Pragma("unroll")                                                 \
            for (int j = 0; j < 4; ++j) {                                     \
                __bf16 h0 = (__bf16)v0[j], h1 = (__bf16)v1[j];                \
                ah[j] = h0;  ah[4 + j] = h1;                                  \
                al[j]     = (__bf16)(v0[j] - (float)h0);                      \
                al[4 + j] = (__bf16)(v1[j] - (float)h1);                      \
            }                                                                 \
            bf8v w = *(const bf8v*)&Wlds[c][ks * 32 + kq];                    \
            xa0 = __builtin_amdgcn_mfma_f32_16x16x32_bf16(ah, w, xa0, 0, 0, 0); \
            xa1 = __builtin_amdgcn_mfma_f32_16x16x32_bf16(al, w, xa1, 0, 0, 0); \
        }                                                                     \
    }

__global__ void __launch_bounds__(256, 1)
lstm_fused(const float* __restrict__ xs, const float* __restrict__ Wi,
           const float* __restrict__ Wh, const float* __restrict__ bias,
           const float* __restrict__ Wo, const float* __restrict__ bo,
           float* __restrict__ out, __bf16* __restrict__ hws,
           unsigned* __restrict__ flags)
{
    __shared__ __bf16 Wlds[16][KTOT + 8];   // 49408 B (bf16-rounded weights)
    __shared__ float  gbuf[64][17];         // 4352 B
    __shared__ float  obuf[4][16][17];      // 4352 B   (total 58112 B)

    const int tid = threadIdx.x;
    const int blk = blockIdx.x;       // 0..255
    const int j0  = blk * 4;
    const int ob0 = (blk >> 5) * 8;   // out-proj batch group (8 batches)
    const int oc0 = (blk & 31) * 16;  // out-proj col group (16 cols)

    // Stage resident gate-weight slab (f32 -> bf16)
    for (int idx = tid; idx < 16 * KTOT; idx += 256) {
        int k = idx >> 4, c = idx & 15;
        int gc = (c >> 2) * H_ + j0 + (c & 3);
        float w = (k < IN_) ? Wi[(size_t)k * G4_ + gc]
                            : Wh[(size_t)(k - IN_) * G4_ + gc];
        Wlds[c][k] = (__bf16)w;
    }
    __syncthreads();

    const int lane = tid & 63;
    const int wave = tid >> 6;
    const int c    = lane & 15;
    const int quad = lane >> 4;
    const int rowA = wave * 16 + c;   // batch row for gate A-frags
    const int kq   = quad * 8;

    const float biasv = bias[(c >> 2) * H_ + j0 + (c & 3)];

    // Hoist step-invariant Wo fragments into registers (f32 -> bf16)
    bf8v wof[8];
    #pragma unroll
    for (int kk = 0; kk < 8; ++kk) {
        int kbase = wave * 256 + kk * 32 + kq;
        #pragma unroll
        for (int j = 0; j < 8; ++j)
            wof[kk][j] = (__bf16)Wo[(size_t)(kbase + j) * OUT_ + oc0 + c];
    }

    // recurrent cell state: thread owns (batch = tid>>2, j = j0 + (tid&3))
    float c_reg = 0.f;
    const int bb = tid >> 2;
    const int jo = tid & 3;

    // x partial accumulators for the upcoming step (prologue: t=0)
    f4v xacc0 = {0.f, 0.f, 0.f, 0.f};
    f4v xacc1 = {0.f, 0.f, 0.f, 0.f};
    X_PRE(0, xacc0, xacc1);

    const size_t bufsz = (size_t)2 * B_ * H_;   // bf16 per buffer (hi+lo planes)

    for (int t = 0; t < T_; ++t) {
        const int br = (t + 2) % 3;   // buffer holding h_{t-1}
        const int bw = t % 3;         // buffer for h_t
        const __bf16* hhi_p = hws + (size_t)br * bufsz;
        const __bf16* hlo_p = hhi_p + B_ * H_;
        __bf16* hhi_c = hws + (size_t)bw * bufsz;
        __bf16* hlo_c = hhi_c + B_ * H_;

        // ---- phase A: gate MFMA for step t (x part precomputed) ----
        f4v acc0 = xacc0;   // hi-product chain
        f4v acc1 = xacc1;   // lo-product chain
        if (t > 0) {
            const __bf16* hh = hhi_p + (size_t)rowA * H_ + kq;
            const __bf16* hl = hlo_p + (size_t)rowA * H_ + kq;
            #pragma unroll
            for (int ks = 0; ks < 32; ++ks) {
                bf8v ah = *(const bf8v*)(hh + ks * 32);
                bf8v al = *(const bf8v*)(hl + ks * 32);
                bf8v w  = *(const bf8v*)&Wlds[c][IN_ + ks * 32 + kq];
                acc0 = __builtin_amdgcn_mfma_f32_16x16x32_bf16(ah, w, acc0, 0, 0, 0);
                acc1 = __builtin_amdgcn_mfma_f32_16x16x32_bf16(al, w, acc1, 0, 0, 0);
            }
        }
        f4v acc = acc0 + acc1;
        #pragma unroll
        for (int r = 0; r < 4; ++r)
            gbuf[wave * 16 + quad * 4 + r][c] = acc[r] + biasv;  // C: col=c, row=quad*4+r
        __syncthreads();

        // ---- phase B: elementwise cell update, write h_t (hi+lo, write-through) ----
        {
            float gi = gbuf[bb][jo];
            float gf = gbuf[bb][4 + jo];
            float gg = gbuf[bb][8 + jo];
            float go = gbuf[bb][12 + jo];
            c_reg = sigm(gf) * c_reg + sigm(gi) * tanh_f(gg);
            float hn = sigm(go) * tanh_f(c_reg);
            __bf16 hh = (__bf16)hn;
            store_bf16_wt(&hhi_c[(size_t)bb * H_ + j0 + jo], hh);
            store_bf16_wt(&hlo_c[(size_t)bb * H_ + j0 + jo], (__bf16)(hn - (float)hh));
        }

        // ==== grid barrier; A2/B2/x-pre all live in the wait shadow ====
        __syncthreads();   // drains vmcnt: all waves' sc0sc1 h stores ack'd at LLC
        const unsigned tgt = (unsigned)(t + 1);
        if (tid == 0) {
            unsigned* p = &flags[blk * 16];
            asm volatile("global_store_dword %0, %1, off sc0 sc1"
                         :: "v"(p), "v"(tgt) : "memory");
        }

        // ---- shadow 1: out-proj partial for step t-1 (reads h_{t-1}).
        // Race-free: buf br is next overwritten at step t+2's phase B,
        // ordered after barrier(t+1), which needs our flag(t+1), set
        // after this code.
        if (t > 0) {
            f4v oac = {0.f, 0.f, 0.f, 0.f};
            #pragma unroll
            for (int kk = 0; kk < 8; ++kk) {
                int kbase = wave * 256 + kk * 32 + kq;
                bf8v ah = {}, al = {};
                if (c < 8) {   // A rows 8..15 zero (8 batches per tile)
                    ah = *(const bf8v*)&hhi_p[(size_t)(ob0 + c) * H_ + kbase];
                    al = *(const bf8v*)&hlo_p[(size_t)(ob0 + c) * H_ + kbase];
                }
                oac = __builtin_amdgcn_mfma_f32_16x16x32_bf16(ah, wof[kk], oac, 0, 0, 0);
                oac = __builtin_amdgcn_mfma_f32_16x16x32_bf16(al, wof[kk], oac, 0, 0, 0);
            }
            #pragma unroll
            for (int r = 0; r < 4; ++r)
                obuf[wave][quad * 4 + r][c] = oac[r];
        }
        __syncthreads();   // obuf visible to reducers (intra-block)

        // ---- shadow 2: reduce out-proj partials, store out[:, t-1, :] ----
        if (t > 0 && tid < 128) {
            int m = tid >> 4, cc = tid & 15;
            float v = obuf[0][m][cc] + obuf[1][m][cc] + obuf[2][m][cc] + obuf[3][m][cc]
                    + bo[oc0 + cc];
            out[(((size_t)(ob0 + m)) * T_ + (t - 1)) * OUT_ + oc0 + cc] = v;
        }

        // ---- shadow 3: x-part of step t+1 (no dependence on h_t) ----
        xacc0 = (f4v){0.f, 0.f, 0.f, 0.f};
        xacc1 = (f4v){0.f, 0.f, 0.f, 0.f};
        if (t + 1 < T_) {
            X_PRE(t + 1, xacc0, xacc1);
        }
        asm volatile("" ::: "memory");   // pin shadow loads above the poll

        // ---- wait ----
        if (tid < 64) {
            const int lane2 = tid;
            for (;;) {
                unsigned m0 = __hip_atomic_load(&flags[(lane2 * 4 + 0) * 16],
                                                __ATOMIC_RELAXED, __HIP_MEMORY_SCOPE_AGENT);
                unsigned m1 = __hip_atomic_load(&flags[(lane2 * 4 + 1) * 16],
                                                __ATOMIC_RELAXED, __HIP_MEMORY_SCOPE_AGENT);
                unsigned m2 = __hip_atomic_load(&flags[(lane2 * 4 + 2) * 16],
                                                __ATOMIC_RELAXED, __HIP_MEMORY_SCOPE_AGENT);
                unsigned m3 = __hip_atomic_load(&flags[(lane2 * 4 + 3) * 16],
                                                __ATOMIC_RELAXED, __HIP_MEMORY_SCOPE_AGENT);
                bool ok = (m0 >= tgt) & (m1 >= tgt) & (m2 >= tgt) & (m3 >= tgt);
                if (__all(ok)) break;
                __builtin_amdgcn_s_sleep(1);
            }
            __builtin_amdgcn_fence(__ATOMIC_ACQUIRE, "agent");   // one inv: h fresh
        }
        __syncthreads();
    }

    // ---- epilogue: out-proj for t = T-1 (h_{T-1} in buf (T-1)%3 = 0) ----
    {
        const __bf16* hhi_l = hws;            // buf 0
        const __bf16* hlo_l = hws + B_ * H_;
        f4v oac = {0.f, 0.f, 0.f, 0.f};
        #pragma unroll
        for (int kk = 0; kk < 8; ++kk) {
            int kbase = wave * 256 + kk * 32 + kq;
            bf8v ah = {}, al = {};
            if (c < 8) {
                ah = *(const bf8v*)&hhi_l[(size_t)(ob0 + c) * H_ + kbase];
                al = *(const bf8v*)&hlo_l[(size_t)(ob0 + c) * H_ + kbase];
            }
            oac = __builtin_amdgcn_mfma_f32_16x16x32_bf16(ah, wof[kk], oac, 0, 0, 0);
            oac = __builtin_amdgcn_mfma_f32_16x16x32_bf16(al, wof[kk], oac, 0, 0, 0);
        }
        #pragma unroll
        for (int r = 0; r < 4; ++r)
            obuf[wave][quad * 4 + r][c] = oac[r];
        __syncthreads();
        if (tid < 128) {
            int m = tid >> 4, cc = tid & 15;
            float v = obuf[0][m][cc] + obuf[1][m][cc] + obuf[2][m][cc] + obuf[3][m][cc]
                    + bo[oc0 + cc];
            out[(((size_t)(ob0 + m)) * T_ + (T_ - 1)) * OUT_ + oc0 + cc] = v;
        }
    }
}

extern "C" void kernel_launch(void* const* d_in, const int* in_sizes, int n_in,
                              void* d_out, int out_size, void* d_ws, size_t ws_size,
                              hipStream_t stream) {
    const float* xs = (const float*)d_in[0];
    const float* Wi = (const float*)d_in[1];
    const float* Wh = (const float*)d_in[2];
    const float* b  = (const float*)d_in[3];
    const float* Wo = (const float*)d_in[4];
    const float* bo = (const float*)d_in[5];
    float* out = (float*)d_out;

    // ws layout: [0,16K) flag vector (256 x 64B-padded, zeroed);
    //            [64K, +768K) h TRIPLE buffer (hi/lo planes, bf16)
    unsigned* flags = (unsigned*)d_ws;         // flags[i*16], i = 0..255
    __bf16*   hws   = (__bf16*)((char*)d_ws + 65536);

    hipMemsetAsync(d_ws, 0, 32768, stream);    // reset flags (graph-capture safe)

    void* args[] = {(void*)&xs, (void*)&Wi, (void*)&Wh, (void*)&b,
                    (void*)&Wo, (void*)&bo, (void*)&out, (void*)&hws,
                    (void*)&flags};
    hipLaunchCooperativeKernel((void*)lstm_fused, dim3(256), dim3(256), args, 0, stream);
}

// Round 10
// 3767.760 us; speedup vs baseline: 1.0992x; 1.0992x over previous
//
#include <hip/hip_runtime.h>
#include <hip/hip_cooperative_groups.h>

// LSTM: B=64, T=256, IN=512, H=1024 (4H=4096), OUT=512. I/O f32.
// Round-20 = r19 structure with the PER-STEP ACQUIRE FENCE ELIMINATED
// by making all h READS LLC-direct via inline-asm global_load sc0 sc1.
//   r18/r19 nulls: no actual barrier wait exists (lockstep blocks);
//   step time = serial work + barrier mechanics. The unmodeled term is
//   the agent-acquire fence: full 4MB L2 invalidate x32 blocks/XCD/step
//   (r10->r11 showed agent cache-maintenance ops cost ~5us/step class).
//   It also forces x (read-only!) to refetch from LLC every step.
// This round:
//   - h gate loads: asm global_load_dwordx4 sc0 sc1 (r15 proved
//     volatile does NOT bypass L2; asm store with these flags proven
//     since r11), counted-vmcnt pipeline: 2 groups x 16 loads in
//     flight, s_waitcnt vmcnt(16) + sched_barrier(0) per group
//     (in-order retirement makes oldest-group consume safe under any
//     stray-load interleaving).
//   - A2 + epilogue h loads: batched asm + vmcnt(0) + sched_barrier.
//   - NO fence anywhere: h stores (sc0sc1) -> vmcnt drain at
//     __syncthreads -> flag store (sc0sc1) -> pollers see flag at LLC
//     => h at LLC; readers read LLC directly.
//   - x/Wi/Wh/Wo/Wlds stay permanently L2-resident (never invalidated).
// MFMA accumulation order unchanged -> bitwise-identical numerics
// (absmax 7.8e-3).
// ws: [0,16K) flags; [64K, +768K) h triple buffer (hi/lo planes).

#define B_   64
#define T_   256
#define IN_  512
#define H_   1024
#define G4_  4096
#define OUT_ 512
#define KTOT 1536   // IN_ + H_

typedef __bf16 bf8v  __attribute__((ext_vector_type(8)));
typedef float  f4v   __attribute__((ext_vector_type(4)));

__device__ __forceinline__ float sigm(float x) { return 1.f / (1.f + __expf(-x)); }
__device__ __forceinline__ float tanh_f(float x) { return 1.f - 2.f / (__expf(2.f * x) + 1.f); }

// LLC-direct 16B load (bypass L1+L2). Tracked manually via vmcnt.
#define GLOAD(dst, p) \
    asm volatile("global_load_dwordx4 %0, %1, off sc0 sc1" \
                 : "=v"(dst) : "v"(p))

#define VM_WAIT(n) do { \
    asm volatile("s_waitcnt vmcnt(" #n ")"); \
    __builtin_amdgcn_sched_barrier(0); \
} while (0)

// Write-through store of one bf16, bypassing L1 (sc0) and L2 (sc1).
__device__ __forceinline__ void store_bf16_wt(__bf16* p, __bf16 v) {
    union { __bf16 b; unsigned short s; } cv; cv.b = v;
    unsigned w = cv.s;
    asm volatile("global_store_short %0, %1, off sc0 sc1"
                 :: "v"(p), "v"(w) : "memory");
}

// x-part of the gate GEMM for timestep tt (r12 order). Plain cached
// loads: x is read-only and, with no invalidates, stays L2-resident.
#define X_PRE(tt, xa0, xa1)                                                   \
    {                                                                         \
        const float* xrow = xs + ((size_t)rowA * T_ + (size_t)(tt)) * IN_ + kq; \
        _Pragma("unroll")                                                     \
        for (int ks = 0; ks < 16; ++ks) {                                     \
            f4v v0 = *(const f4v*)(xrow + ks * 32);                           \
            f4v v1 = *(const f4v*)(xrow + ks * 32 + 4);                       \
            bf8v ah, al;                                                      \
            _Pragma("unroll")                                                 \
            for (int j = 0; j < 4; ++j) {                                     \
                __bf16 h0 = (__bf16)v0[j], h1 = (__bf16)v1[j];                \
                ah[j] = h0;  ah[4 + j] = h1;                                  \
                al[j]     = (__bf16)(v0[j] - (float)h0);                      \
                al[4 + j] = (__bf16)(v1[j] - (float)h1);                      \
            }                                                                 \
            bf8v w = *(const bf8v*)&Wlds[c][ks * 32 + kq];                    \
            xa0 = __builtin_amdgcn_mfma_f32_16x16x32_bf16(ah, w, xa0, 0, 0, 0); \
            xa1 = __builtin_amdgcn_mfma_f32_16x16x32_bf16(al, w, xa1, 0, 0, 0); \
        }                                                                     \
    }

// issue one 8-iter group of gate h loads (16 LLC-direct loads)
#define GISSUE(Hreg, Lreg, kb)                                                \
    _Pragma("unroll")                                                         \
    for (int i = 0; i < 8; ++i) {                                             \
        GLOAD(Hreg[i], hh + ((kb) + i) * 32);                                 \
        GLOAD(Lreg[i], hl + ((kb) + i) * 32);                                 \
    }

// consume one 8-iter group (order identical to r12's ks sweep)
#define GCONSUME(Hreg, Lreg, kb)                                              \
    _Pragma("unroll")                                                         \
    for (int i = 0; i < 8; ++i) {                                             \
        bf8v w = *(const bf8v*)&Wlds[c][IN_ + ((kb) + i) * 32 + kq];          \
        acc0 = __builtin_amdgcn_mfma_f32_16x16x32_bf16(                       \
            __builtin_bit_cast(bf8v, Hreg[i]), w, acc0, 0, 0, 0);             \
        acc1 = __builtin_amdgcn_mfma_f32_16x16x32_bf16(                       \
            __builtin_bit_cast(bf8v, Lreg[i]), w, acc1, 0, 0, 0);             \
    }

__global__ void __launch_bounds__(256, 1)
lstm_fused(const float* __restrict__ xs, const float* __restrict__ Wi,
           const float* __restrict__ Wh, const float* __restrict__ bias,
           const float* __restrict__ Wo, const float* __restrict__ bo,
           float* __restrict__ out, __bf16* __restrict__ hws,
           unsigned* __restrict__ flags)
{
    __shared__ __bf16 Wlds[16][KTOT + 8];   // 49408 B (bf16-rounded weights)
    __shared__ float  gbuf[64][17];         // 4352 B
    __shared__ float  obuf[4][16][17];      // 4352 B   (total 58112 B)

    const int tid = threadIdx.x;
    const int blk = blockIdx.x;       // 0..255
    const int j0  = blk * 4;
    const int ob0 = (blk >> 5) * 8;   // out-proj batch group (8 batches)
    const int oc0 = (blk & 31) * 16;  // out-proj col group (16 cols)

    // Stage resident gate-weight slab (f32 -> bf16)
    for (int idx = tid; idx < 16 * KTOT; idx += 256) {
        int k = idx >> 4, c = idx & 15;
        int gc = (c >> 2) * H_ + j0 + (c & 3);
        float w = (k < IN_) ? Wi[(size_t)k * G4_ + gc]
                            : Wh[(size_t)(k - IN_) * G4_ + gc];
        Wlds[c][k] = (__bf16)w;
    }
    __syncthreads();

    const int lane = tid & 63;
    const int wave = tid >> 6;
    const int c    = lane & 15;
    const int quad = lane >> 4;
    const int rowA = wave * 16 + c;   // batch row for gate A-frags
    const int kq   = quad * 8;

    const float biasv = bias[(c >> 2) * H_ + j0 + (c & 3)];

    // Hoist step-invariant Wo fragments into registers (f32 -> bf16)
    bf8v wof[8];
    #pragma unroll
    for (int kk = 0; kk < 8; ++kk) {
        int kbase = wave * 256 + kk * 32 + kq;
        #pragma unroll
        for (int j = 0; j < 8; ++j)
            wof[kk][j] = (__bf16)Wo[(size_t)(kbase + j) * OUT_ + oc0 + c];
    }

    // recurrent cell state: thread owns (batch = tid>>2, j = j0 + (tid&3))
    float c_reg = 0.f;
    const int bb = tid >> 2;
    const int jo = tid & 3;

    // x partial accumulators for the upcoming step (prologue: t=0)
    f4v xacc0 = {0.f, 0.f, 0.f, 0.f};
    f4v xacc1 = {0.f, 0.f, 0.f, 0.f};
    X_PRE(0, xacc0, xacc1);

    const size_t bufsz = (size_t)2 * B_ * H_;   // bf16 per buffer (hi+lo planes)

    for (int t = 0; t < T_; ++t) {
        asm volatile("" ::: "memory");   // pin loads below the barrier exit
        const int br = (t + 2) % 3;   // buffer holding h_{t-1}
        const int bw = t % 3;         // buffer for h_t
        const __bf16* hhi_p = hws + (size_t)br * bufsz;
        const __bf16* hlo_p = hhi_p + B_ * H_;
        __bf16* hhi_c = hws + (size_t)bw * bufsz;
        __bf16* hlo_c = hhi_c + B_ * H_;

        // ---- phase A: gate MFMA for step t (x part precomputed) ----
        f4v acc0 = xacc0;   // hi-product chain
        f4v acc1 = xacc1;   // lo-product chain
        if (t > 0) {
            const __bf16* hh = hhi_p + (size_t)rowA * H_ + kq;
            const __bf16* hl = hlo_p + (size_t)rowA * H_ + kq;
            f4v Ah0[8], Al0[8], Ah1[8], Al1[8];
            GISSUE(Ah0, Al0, 0);      // G0 in flight (16)
            GISSUE(Ah1, Al1, 8);      // G1 in flight (32 total)
            VM_WAIT(16);              // G0 retired
            GCONSUME(Ah0, Al0, 0);
            GISSUE(Ah0, Al0, 16);     // G2
            VM_WAIT(16);              // G1 retired
            GCONSUME(Ah1, Al1, 8);
            GISSUE(Ah1, Al1, 24);     // G3
            VM_WAIT(16);              // G2 retired
            GCONSUME(Ah0, Al0, 16);
            VM_WAIT(0);               // G3 retired
            GCONSUME(Ah1, Al1, 24);
        }
        f4v acc = acc0 + acc1;
        #pragma unroll
        for (int r = 0; r < 4; ++r)
            gbuf[wave * 16 + quad * 4 + r][c] = acc[r] + biasv;  // C: col=c, row=quad*4+r
        __syncthreads();

        // ---- phase B: elementwise cell update, write h_t (hi+lo, write-through) ----
        {
            float gi = gbuf[bb][jo];
            float gf = gbuf[bb][4 + jo];
            float gg = gbuf[bb][8 + jo];
            float go = gbuf[bb][12 + jo];
            c_reg = sigm(gf) * c_reg + sigm(gi) * tanh_f(gg);
            float hn = sigm(go) * tanh_f(c_reg);
            __bf16 hh2 = (__bf16)hn;
            store_bf16_wt(&hhi_c[(size_t)bb * H_ + j0 + jo], hh2);
            store_bf16_wt(&hlo_c[(size_t)bb * H_ + j0 + jo], (__bf16)(hn - (float)hh2));
        }

        // ==== arrive; shadow work; poll (NO fence anywhere) ====
        __syncthreads();   // drains vmcnt: all waves' sc0sc1 h stores ack'd at LLC
        const unsigned tgt = (unsigned)(t + 1);
        if (tid == 0) {
            unsigned* p = &flags[blk * 16];
            asm volatile("global_store_dword %0, %1, off sc0 sc1"
                         :: "v"(p), "v"(tgt) : "memory");
        }

        // ---- shadow 1: out-proj partial for step t-1 (LLC-direct reads).
        // Race-free: buf br next overwritten at step t+2's phase B, which
        // is ordered after barrier(t+1), which needs our flag(t+1), set
        // before this point.
        if (t > 0) {
            f4v Oh[8], Ol[8];
            #pragma unroll
            for (int kk = 0; kk < 8; ++kk) {
                Oh[kk] = (f4v){0.f, 0.f, 0.f, 0.f};
                Ol[kk] = (f4v){0.f, 0.f, 0.f, 0.f};
            }
            const __bf16* orh = hhi_p + (size_t)(ob0 + c) * H_;
            const __bf16* orl = hlo_p + (size_t)(ob0 + c) * H_;
            if (c < 8) {   // A rows 8..15 zero (8 batches per tile)
                #pragma unroll
                for (int kk = 0; kk < 8; ++kk) {
                    GLOAD(Oh[kk], orh + wave * 256 + kk * 32 + kq);
                    GLOAD(Ol[kk], orl + wave * 256 + kk * 32 + kq);
                }
            }
            VM_WAIT(0);
            f4v oac = {0.f, 0.f, 0.f, 0.f};
            #pragma unroll
            for (int kk = 0; kk < 8; ++kk) {
                oac = __builtin_amdgcn_mfma_f32_16x16x32_bf16(
                    __builtin_bit_cast(bf8v, Oh[kk]), wof[kk], oac, 0, 0, 0);
                oac = __builtin_amdgcn_mfma_f32_16x16x32_bf16(
                    __builtin_bit_cast(bf8v, Ol[kk]), wof[kk], oac, 0, 0, 0);
            }
            #pragma unroll
            for (int r = 0; r < 4; ++r)
                obuf[wave][quad * 4 + r][c] = oac[r];
        }
        __syncthreads();   // obuf visible to reducers (intra-block)

        // ---- shadow 2: reduce out-proj partials, store out[:, t-1, :] ----
        if (t > 0 && tid < 128) {
            int m = tid >> 4, cc = tid & 15;
            float v = obuf[0][m][cc] + obuf[1][m][cc] + obuf[2][m][cc] + obuf[3][m][cc]
                    + bo[oc0 + cc];
            out[(((size_t)(ob0 + m)) * T_ + (t - 1)) * OUT_ + oc0 + cc] = v;
        }

        // ---- shadow 3: x-part of step t+1 (no dependence on h_t) ----
        xacc0 = (f4v){0.f, 0.f, 0.f, 0.f};
        xacc1 = (f4v){0.f, 0.f, 0.f, 0.f};
        if (t + 1 < T_) {
            X_PRE(t + 1, xacc0, xacc1);
        }
        asm volatile("" ::: "memory");   // pin shadow loads above the poll

        // ---- wait (relaxed poll; no fence: h readers are LLC-direct) ----
        if (tid < 64) {
            const int lane2 = tid;
            for (;;) {
                unsigned m0 = __hip_atomic_load(&flags[(lane2 * 4 + 0) * 16],
                                                __ATOMIC_RELAXED, __HIP_MEMORY_SCOPE_AGENT);
                unsigned m1 = __hip_atomic_load(&flags[(lane2 * 4 + 1) * 16],
                                                __ATOMIC_RELAXED, __HIP_MEMORY_SCOPE_AGENT);
                unsigned m2 = __hip_atomic_load(&flags[(lane2 * 4 + 2) * 16],
                                                __ATOMIC_RELAXED, __HIP_MEMORY_SCOPE_AGENT);
                unsigned m3 = __hip_atomic_load(&flags[(lane2 * 4 + 3) * 16],
                                                __ATOMIC_RELAXED, __HIP_MEMORY_SCOPE_AGENT);
                bool ok = (m0 >= tgt) & (m1 >= tgt) & (m2 >= tgt) & (m3 >= tgt);
                if (__all(ok)) break;
                __builtin_amdgcn_s_sleep(1);
            }
        }
        __syncthreads();
    }

    // ---- epilogue: out-proj for t = T-1 (h_{T-1} in buf (T-1)%3 = 0) ----
    {
        const __bf16* hhi_l = hws;            // buf 0
        const __bf16* hlo_l = hws + B_ * H_;
        f4v Oh[8], Ol[8];
        #pragma unroll
        for (int kk = 0; kk < 8; ++kk) {
            Oh[kk] = (f4v){0.f, 0.f, 0.f, 0.f};
            Ol[kk] = (f4v){0.f, 0.f, 0.f, 0.f};
        }
        const __bf16* orh = hhi_l + (size_t)(ob0 + c) * H_;
        const __bf16* orl = hlo_l + (size_t)(ob0 + c) * H_;
        if (c < 8) {
            #pragma unroll
            for (int kk = 0; kk < 8; ++kk) {
                GLOAD(Oh[kk], orh + wave * 256 + kk * 32 + kq);
                GLOAD(Ol[kk], orl + wave * 256 + kk * 32 + kq);
            }
        }
        VM_WAIT(0);
        f4v oac = {0.f, 0.f, 0.f, 0.f};
        #pragma unroll
        for (int kk = 0; kk < 8; ++kk) {
            oac = __builtin_amdgcn_mfma_f32_16x16x32_bf16(
                __builtin_bit_cast(bf8v, Oh[kk]), wof[kk], oac, 0, 0, 0);
            oac = __builtin_amdgcn_mfma_f32_16x16x32_bf16(
                __builtin_bit_cast(bf8v, Ol[kk]), wof[kk], oac, 0, 0, 0);
        }
        #pragma unroll
        for (int r = 0; r < 4; ++r)
            obuf[wave][quad * 4 + r][c] = oac[r];
        __syncthreads();
        if (tid < 128) {
            int m = tid >> 4, cc = tid & 15;
            float v = obuf[0][m][cc] + obuf[1][m][cc] + obuf[2][m][cc] + obuf[3][m][cc]
                    + bo[oc0 + cc];
            out[(((size_t)(ob0 + m)) * T_ + (T_ - 1)) * OUT_ + oc0 + cc] = v;
        }
    }
}

extern "C" void kernel_launch(void* const* d_in, const int* in_sizes, int n_in,
                              void* d_out, int out_size, void* d_ws, size_t ws_size,
                              hipStream_t stream) {
    const float* xs = (const float*)d_in[0];
    const float* Wi = (const float*)d_in[1];
    const float* Wh = (const float*)d_in[2];
    const float* b  = (const float*)d_in[3];
    const float* Wo = (const float*)d_in[4];
    const float* bo = (const float*)d_in[5];
    float* out = (float*)d_out;

    // ws layout: [0,16K) flag vector (256 x 64B-padded, zeroed);
    //            [64K, +768K) h TRIPLE buffer (hi/lo planes, bf16)
    unsigned* flags = (unsigned*)d_ws;         // flags[i*16], i = 0..255
    __bf16*   hws   = (__bf16*)((char*)d_ws + 65536);

    hipMemsetAsync(d_ws, 0, 32768, stream);    // reset flags (graph-capture safe)

    void* args[] = {(void*)&xs, (void*)&Wi, (void*)&Wh, (void*)&b,
                    (void*)&Wo, (void*)&bo, (void*)&out, (void*)&hws,
                    (void*)&flags};
    hipLaunchCooperativeKernel((void*)lstm_fused, dim3(256), dim3(256), args, 0, stream);
}